// Round 1
// 721.459 us; speedup vs baseline: 1.0124x; 1.0124x over previous
//
#include <hip/hip_runtime.h>

// Router: logits = x @ W^T (fp32-exact via 3-way bf16 split + 6 MFMA passes),
// softmax -> argmax one-hot + top prob + logits.
// x: [65536, 2048] fp32, W: [64, 2048] fp32.
// Out (flat float): onehot [T*64] | top_prob [T] | logits [T*64].
//
// V2: W planes precomputed ONCE by a prologue kernel into d_ws (bf16, pre-swizzled
// per chunk), removing the per-block-per-chunk W re-split (512x redundant VALU).
// Main kernel stages ready bf16 planes (issue-early/write-late, double-buffered LDS,
// XOR-swizzled rows -> conflict-free ds_read_b128). split3 uses v_perm_b32 pairing.

constexpr int T_TOK = 65536;
constexpr int DM    = 2048;
constexpr int NE    = 64;
constexpr int BM    = 128;            // tokens per block (4 waves x 32)
constexpr int BK    = 64;             // k chunk
constexpr int NCH   = DM / BK;        // 32
constexpr int PLB   = NE * BK * 2;    // 8192 B per plane per chunk
constexpr int CHB   = 3 * PLB;        // 24576 B per chunk (h,m,l planes)
// d_ws usage: NCH * CHB = 786432 bytes of W planes.

typedef __attribute__((ext_vector_type(8))) short bf16x8;
typedef __attribute__((ext_vector_type(4))) float f32x4;
typedef __attribute__((ext_vector_type(4))) unsigned int u32x4;

__device__ __forceinline__ unsigned int pack_hi16(unsigned int lo, unsigned int hi) {
    // (lo>>16) | (hi & 0xFFFF0000) in one v_perm_b32
    return __builtin_amdgcn_perm(hi, lo, 0x07060302u);
}

// Exact truncating split of 8 fp32 into 3 bf16 planes (packed as 4 dwords each):
// x == h + m + l bitwise (24 mantissa bits = 3 x 8; bf16 exp range == fp32).
// Identical values to V1's split3 — only the packing codegen differs.
__device__ __forceinline__ void split3x8(const f32x4& a, const f32x4& b,
                                         u32x4& h, u32x4& m, u32x4& l) {
#pragma unroll
    for (int p = 0; p < 4; ++p) {
        const float x0 = (p < 2) ? a[2 * p]     : b[2 * p - 4];
        const float x1 = (p < 2) ? a[2 * p + 1] : b[2 * p - 3];
        const unsigned u00 = __float_as_uint(x0);
        const unsigned u01 = __float_as_uint(x1);
        h[p] = pack_hi16(u00, u01);
        const float r10 = x0 - __uint_as_float(u00 & 0xFFFF0000u);
        const float r11 = x1 - __uint_as_float(u01 & 0xFFFF0000u);
        const unsigned u10 = __float_as_uint(r10);
        const unsigned u11 = __float_as_uint(r11);
        m[p] = pack_hi16(u10, u11);
        const float r20 = r10 - __uint_as_float(u10 & 0xFFFF0000u);
        const float r21 = r11 - __uint_as_float(u11 & 0xFFFF0000u);
        l[p] = pack_hi16(__float_as_uint(r20), __float_as_uint(r21));
    }
}

// ---- prologue: split W into 3 bf16 planes, chunked + XOR-swizzled, into d_ws.
// Layout: ws[kc*CHB + plane*PLB + e*128 + ((gi ^ (e&7))<<4)] holds the 16B group
// of shorts k = kc*64 + gi*8 .. +8 of expert e.
__global__ __launch_bounds__(256)
void wsplit(const float* __restrict__ W, unsigned char* __restrict__ wq)
{
    const int gid = blockIdx.x * 256 + threadIdx.x;   // 16384 threads
    const int e   = gid >> 8;                         // expert 0..63
    const int g   = gid & 255;                        // 8-elem group within row
    const int k0  = g << 3;
    const int kc  = k0 >> 6;                          // chunk 0..31
    const int gi  = (k0 >> 3) & 7;                    // group within chunk row

    const float* p = W + (long)e * DM + k0;
    const f32x4 a  = *(const f32x4*)p;
    const f32x4 bb = *(const f32x4*)(p + 4);
    u32x4 h, m, l;
    split3x8(a, bb, h, m, l);

    unsigned char* dst = wq + (long)kc * CHB + e * 128 + ((gi ^ (e & 7)) << 4);
    *(u32x4*)(dst)           = h;
    *(u32x4*)(dst + PLB)     = m;
    *(u32x4*)(dst + 2 * PLB) = l;
}

__global__ __launch_bounds__(256, 2)
void router_mfma(const float* __restrict__ x, const unsigned char* __restrict__ wq,
                 float* __restrict__ onehot, float* __restrict__ topp,
                 float* __restrict__ logits)
{
    __shared__ __align__(16) unsigned char wlds[2 * CHB];   // 48 KB double buffer

    const int tid  = threadIdx.x;
    const int lane = tid & 63;
    const int wave = tid >> 6;
    const int r16  = lane & 15;     // MFMA m/n lane index
    const int quad = lane >> 4;     // MFMA k-group / row-group

    const long blk_t0 = (long)blockIdx.x * BM;
    const long trow0  = blk_t0 + wave * 32 + r16;   // mt=0 token row
    const long trow1  = trow0 + 16;                 // mt=1

    const float* xp0 = x + trow0 * DM + quad * 8;
    const float* xp1 = x + trow1 * DM + quad * 8;

    const unsigned char* wsrc = wq + tid * 16;      // linear staging source

    f32x4 acc[2][4];
#pragma unroll
    for (int mt = 0; mt < 2; ++mt)
#pragma unroll
        for (int nt = 0; nt < 4; ++nt) acc[mt][nt] = (f32x4){0.f, 0.f, 0.f, 0.f};

    f32x4 xn[2][2][2];   // x prefetch regs [mt][ks][2 x float4]
    u32x4 af[2][2][3];   // A fragments [mt][ks][plane] (packed bf16)
    u32x4 wreg[6];       // W staging regs (96 B/thread)

    // ---- preload chunk 0
#pragma unroll
    for (int mt = 0; mt < 2; ++mt)
#pragma unroll
        for (int ks = 0; ks < 2; ++ks) {
            const float* p = (mt ? xp1 : xp0) + ks * 32;
            xn[mt][ks][0] = *(const f32x4*)p;
            xn[mt][ks][1] = *(const f32x4*)(p + 4);
        }
#pragma unroll
    for (int it = 0; it < 6; ++it)
        wreg[it] = *(const u32x4*)(wsrc + it * 4096);

#pragma unroll
    for (int mt = 0; mt < 2; ++mt)
#pragma unroll
        for (int ks = 0; ks < 2; ++ks)
            split3x8(xn[mt][ks][0], xn[mt][ks][1],
                     af[mt][ks][0], af[mt][ks][1], af[mt][ks][2]);
#pragma unroll
    for (int it = 0; it < 6; ++it)
        *(u32x4*)(&wlds[tid * 16 + it * 4096]) = wreg[it];
    __syncthreads();

    const int swz_r = (r16 & 7);

    for (int kc = 0; kc < NCH; ++kc) {
        const int nxt = kc + 1;
        if (nxt < NCH) {
            // issue next-chunk loads early (consumed after the MFMAs)
#pragma unroll
            for (int mt = 0; mt < 2; ++mt)
#pragma unroll
                for (int ks = 0; ks < 2; ++ks) {
                    const float* p = (mt ? xp1 : xp0) + nxt * BK + ks * 32;
                    xn[mt][ks][0] = *(const f32x4*)p;
                    xn[mt][ks][1] = *(const f32x4*)(p + 4);
                }
            const unsigned char* ws2 = wsrc + (long)nxt * CHB;
#pragma unroll
            for (int it = 0; it < 6; ++it)
                wreg[it] = *(const u32x4*)(ws2 + it * 4096);
        }

        // ---- 96 MFMAs on current chunk; B frags from LDS buffer (kc&1)
        const unsigned char* wb = &wlds[(kc & 1) * CHB];
#pragma unroll
        for (int ks = 0; ks < 2; ++ks) {
#pragma unroll
            for (int nt = 0; nt < 4; ++nt) {
                const int eo = (nt * 16 + r16) * 128 +
                               (((((ks << 2) | quad)) ^ swz_r) << 4);
                const bf16x8 bh = *(const bf16x8*)(wb + eo);
                const bf16x8 bm = *(const bf16x8*)(wb + PLB + eo);
                const bf16x8 bl = *(const bf16x8*)(wb + 2 * PLB + eo);
#pragma unroll
                for (int mt = 0; mt < 2; ++mt) {
                    const bf16x8 ah = __builtin_bit_cast(bf16x8, af[mt][ks][0]);
                    const bf16x8 am = __builtin_bit_cast(bf16x8, af[mt][ks][1]);
                    const bf16x8 al = __builtin_bit_cast(bf16x8, af[mt][ks][2]);
                    f32x4 c = acc[mt][nt];
                    c = __builtin_amdgcn_mfma_f32_16x16x32_bf16(ah, bh, c, 0, 0, 0);
                    c = __builtin_amdgcn_mfma_f32_16x16x32_bf16(am, bh, c, 0, 0, 0);
                    c = __builtin_amdgcn_mfma_f32_16x16x32_bf16(al, bh, c, 0, 0, 0);
                    c = __builtin_amdgcn_mfma_f32_16x16x32_bf16(ah, bm, c, 0, 0, 0);
                    c = __builtin_amdgcn_mfma_f32_16x16x32_bf16(am, bm, c, 0, 0, 0);
                    c = __builtin_amdgcn_mfma_f32_16x16x32_bf16(ah, bl, c, 0, 0, 0);
                    acc[mt][nt] = c;
                }
            }
        }

        if (nxt < NCH) {
            // convert prefetched x; write W planes to the other LDS buffer
#pragma unroll
            for (int mt = 0; mt < 2; ++mt)
#pragma unroll
                for (int ks = 0; ks < 2; ++ks)
                    split3x8(xn[mt][ks][0], xn[mt][ks][1],
                             af[mt][ks][0], af[mt][ks][1], af[mt][ks][2]);
            unsigned char* wd = &wlds[(nxt & 1) * CHB + tid * 16];
#pragma unroll
            for (int it = 0; it < 6; ++it)
                *(u32x4*)(wd + it * 4096) = wreg[it];
        }
        __syncthreads();
    }

    // ---- epilogue: C layout col=lane&15 (expert), row=quad*4+reg (token)
#pragma unroll
    for (int mt = 0; mt < 2; ++mt) {
#pragma unroll
        for (int reg = 0; reg < 4; ++reg) {
            const long t = blk_t0 + wave * 32 + mt * 16 + quad * 4 + reg;

            float mval = acc[mt][0][reg];
            int   mi   = r16;
#pragma unroll
            for (int nt = 1; nt < 4; ++nt) {
                const float v = acc[mt][nt][reg];
                if (v > mval) { mval = v; mi = nt * 16 + r16; }  // e ascending in nt
            }
#pragma unroll
            for (int d = 1; d < 16; d <<= 1) {
                const float om = __shfl_xor(mval, d, 64);
                const int   oi = __shfl_xor(mi, d, 64);
                if (om > mval || (om == mval && oi < mi)) { mval = om; mi = oi; }
            }
            float s = 0.f;
#pragma unroll
            for (int nt = 0; nt < 4; ++nt) s += __expf(acc[mt][nt][reg] - mval);
#pragma unroll
            for (int d = 1; d < 16; d <<= 1) s += __shfl_xor(s, d, 64);

            const long ob = t * NE + r16;
#pragma unroll
            for (int nt = 0; nt < 4; ++nt) {
                logits[ob + nt * 16] = acc[mt][nt][reg];
                onehot[ob + nt * 16] = (nt * 16 + r16 == mi) ? 1.0f : 0.0f;
            }
            if (r16 == 0) topp[t] = 1.0f / s;
        }
    }
}

extern "C" void kernel_launch(void* const* d_in, const int* in_sizes, int n_in,
                              void* d_out, int out_size, void* d_ws, size_t ws_size,
                              hipStream_t stream)
{
    (void)in_sizes; (void)n_in; (void)out_size; (void)ws_size;
    const float* x = (const float*)d_in[0];
    const float* W = (const float*)d_in[1];
    float* out = (float*)d_out;

    float* onehot = out;                     // [T*64]
    float* topp   = out + (long)T_TOK * NE;  // [T]
    float* logits = topp + T_TOK;            // [T*64]

    unsigned char* wq = (unsigned char*)d_ws;   // needs NCH*CHB = 768 KB

    wsplit<<<dim3(64), dim3(256), 0, stream>>>(W, wq);
    router_mfma<<<dim3(T_TOK / BM), dim3(256), 0, stream>>>(x, wq, onehot, topp, logits);
}